// Round 4
// baseline (236.519 us; speedup 1.0000x reference)
//
#include <hip/hip_runtime.h>

// GIoU loss, 3D boxes, matched pairs, sum-reduced and negated.
// Box row: [x1, y1, x2, y2, z1, z2] (6 f32).
//
// R4 = ABLATION ROUND. R1 (direct strided) and R2 (global_load_lds+barrier)
// both pinned at 71 us = 2.7 TB/s delivered with VALUBusy 12% — models that
// predicted 5-15 us for both are wrong, so measure the limiter directly:
//   dispatch 1: probe_read_kernel  — pure coalesced dual-stream read-sum
//               (m13/m146-style), the achievable-BW yardstick for this footprint.
//   dispatch 2: giou_direct_kernel — real math, quad-batched for load ILP.
//   dispatch 3: giou_final_kernel  — reduction (uses dispatch 2's partials;
//               probe wrote the same ws slots earlier in stream order, dead).

namespace {

constexpr float kEps     = 1e-7f;
constexpr int   kThreads = 256;     // 4 waves
constexpr int   kBlocks  = 2048;    // 8 blocks/CU nominal, grid-stride

__device__ __forceinline__ float giou1(
    float px1, float py1, float px2, float py2, float pz1, float pz2,
    float tx1, float ty1, float tx2, float ty2, float tz1, float tz2)
{
    float vol1 = (px2 - px1) * (py2 - py1) * (pz2 - pz1);
    float vol2 = (tx2 - tx1) * (ty2 - ty1) * (tz2 - tz1);

    float ix = fmaxf(fminf(px2, tx2) - fmaxf(px1, tx1), 0.0f);
    float iy = fmaxf(fminf(py2, ty2) - fmaxf(py1, ty1), 0.0f);
    float iz = fmaxf(fminf(pz2, tz2) - fmaxf(pz1, tz1), 0.0f);
    float inter = ix * iy * iz;
    float uni = vol1 + vol2 - inter;
    float iou = inter / uni;

    float ex = fmaxf(fmaxf(px2, tx2) - fminf(px1, tx1), 0.0f);
    float ey = fmaxf(fmaxf(py2, ty2) - fminf(py1, ty1), 0.0f);
    float ez = fmaxf(fmaxf(pz2, tz2) - fminf(pz1, tz1), 0.0f);
    float enc = ex * ey * ez + kEps;

    return iou - (enc - uni) / enc;
}

__device__ __forceinline__ double block_reduce(double acc, int tid) {
    #pragma unroll
    for (int off = 32; off > 0; off >>= 1)
        acc += __shfl_down(acc, off, 64);
    __shared__ double smem[kThreads / 64];
    const int lane = tid & 63;
    const int wid  = tid >> 6;
    if (lane == 0) smem[wid] = acc;
    __syncthreads();
    double s = 0.0;
    if (tid == 0) {
        #pragma unroll
        for (int w = 0; w < kThreads / 64; ++w) s += smem[w];
    }
    return s;
}

// ---- Dispatch 1: BW yardstick. Perfectly coalesced, no cross-lane data
// movement, minimal VALU. Measures achievable read BW for this footprint.
__global__ __launch_bounds__(kThreads) void probe_read_kernel(
    const float4* __restrict__ p4, const float4* __restrict__ t4,
    double* __restrict__ partials, int n4)
{
    float acc = 0.0f;
    const int stride = gridDim.x * blockDim.x;
    for (int i = blockIdx.x * blockDim.x + threadIdx.x; i < n4; i += stride) {
        float4 a = p4[i];
        float4 b = t4[i];
        acc += ((a.x + a.y) + (a.z + a.w)) + ((b.x + b.y) + (b.z + b.w));
    }
    double s = block_reduce((double)acc, threadIdx.x);
    if (threadIdx.x == 0) partials[blockIdx.x] = s;   // dead (overwritten by dispatch 2)
}

// ---- Dispatch 2: real GIoU, quad-batched (4 boxes = 2 pairs = 6 float4 per
// array per iter -> 12 independent loads in flight; compiler gets VGPR room).
__global__ __launch_bounds__(kThreads) void giou_direct_kernel(
    const float* __restrict__ pred, const float* __restrict__ targ,
    double* __restrict__ partials, int nquads)
{
    const float4* __restrict__ p4 = reinterpret_cast<const float4*>(pred);
    const float4* __restrict__ t4 = reinterpret_cast<const float4*>(targ);

    double acc = 0.0;
    const int stride = gridDim.x * blockDim.x;
    for (int q = blockIdx.x * blockDim.x + threadIdx.x; q < nquads; q += stride) {
        const size_t b = (size_t)q * 6;
        // Issue all 12 loads before any math (ILP).
        float4 P0 = p4[b + 0], P1 = p4[b + 1], P2 = p4[b + 2];
        float4 P3 = p4[b + 3], P4 = p4[b + 4], P5 = p4[b + 5];
        float4 T0 = t4[b + 0], T1 = t4[b + 1], T2 = t4[b + 2];
        float4 T3 = t4[b + 3], T4 = t4[b + 4], T5 = t4[b + 5];

        // quad layout: box0=(f0.xyzw, f1.xy)  box1=(f1.zw, f2.xyzw)
        //              box2=(f3.xyzw, f4.xy)  box3=(f4.zw, f5.xyzw)
        float g0 = giou1(P0.x, P0.y, P0.z, P0.w, P1.x, P1.y,
                         T0.x, T0.y, T0.z, T0.w, T1.x, T1.y);
        float g1 = giou1(P1.z, P1.w, P2.x, P2.y, P2.z, P2.w,
                         T1.z, T1.w, T2.x, T2.y, T2.z, T2.w);
        float g2 = giou1(P3.x, P3.y, P3.z, P3.w, P4.x, P4.y,
                         T3.x, T3.y, T3.z, T3.w, T4.x, T4.y);
        float g3 = giou1(P4.z, P4.w, P5.x, P5.y, P5.z, P5.w,
                         T4.z, T4.w, T5.x, T5.y, T5.z, T5.w);
        acc += ((double)g0 + (double)g1) + ((double)g2 + (double)g3);
    }

    double s = block_reduce(acc, threadIdx.x);
    if (threadIdx.x == 0) partials[blockIdx.x] = s;
}

// ---- Dispatch 3: final reduction (+ defensive tail for nboxes % 4).
__global__ __launch_bounds__(kThreads) void giou_final_kernel(
    const double* __restrict__ partials, int n,
    const float* __restrict__ pred, const float* __restrict__ targ,
    int tail_start, int nboxes, float* __restrict__ out)
{
    double acc = 0.0;
    for (int i = threadIdx.x; i < n; i += kThreads) acc += partials[i];
    double s = block_reduce(acc, threadIdx.x);
    if (threadIdx.x == 0) {
        for (int bx = tail_start; bx < nboxes; ++bx) {   // dead for N=4e6
            const float* pp = pred + (size_t)bx * 6;
            const float* tt = targ + (size_t)bx * 6;
            s += (double)giou1(pp[0], pp[1], pp[2], pp[3], pp[4], pp[5],
                               tt[0], tt[1], tt[2], tt[3], tt[4], tt[5]);
        }
        out[0] = (float)(-1.0 * s);   // LOSS_WEIGHT * -1 * sum
    }
}

}  // namespace

extern "C" void kernel_launch(void* const* d_in, const int* in_sizes, int n_in,
                              void* d_out, int out_size, void* d_ws, size_t ws_size,
                              hipStream_t stream) {
    const float* pred = (const float*)d_in[0];
    const float* targ = (const float*)d_in[1];
    float* out = (float*)d_out;

    const int nboxes = in_sizes[0] / 6;       // 4,000,000
    const int nquads = nboxes / 4;            // 1,000,000
    const int n4     = in_sizes[0] / 4;       // 6,000,000 float4 per array

    double* partials = (double*)d_ws;         // kBlocks * 8 B = 16 KiB

    probe_read_kernel<<<kBlocks, kThreads, 0, stream>>>(
        (const float4*)pred, (const float4*)targ, partials, n4);
    giou_direct_kernel<<<kBlocks, kThreads, 0, stream>>>(
        pred, targ, partials, nquads);
    giou_final_kernel<<<1, kThreads, 0, stream>>>(
        partials, kBlocks, pred, targ, nquads * 4, nboxes, out);
}